// Round 6
// baseline (398.016 us; speedup 1.0000x reference)
//
#include <hip/hip_runtime.h>
#include <cstdint>
#include <math.h>

// ---------------------------------------------------------------------------
// Bit-exact replication of jax.random with threefry_partitionable=True:
//   split(key)      -> key[i] = threefry(key; hi=0, lo=i)  (foldlike)
//   random_bits 32b -> o0 ^ o1 of threefry(key; hi=0, lo=flat_idx)
//   kp, ku = split(key(42)); key data = (0,42)
//   n_raw = poisson_knuth(kp, 2.0)[row]           (data-INDEPENDENT)
//   n = where(nv>1, min(n_raw, nv-1), 0)
//   scores = where(valid, uniform(ku,(B,128)), -1); drop top-n (stable ties)
//
// Structure (round-4/5 post-mortem: segregate skip rows ACROSS waves; the
// round-5 crash was a lane-63 off-by-one in the compaction mask, fixed here;
// hipMemsetAsync replaced by a zero kernel):
//  * k0 zero_ctrs: ctrs = {0,0}.
//  * k1 pois_part: per-row Knuth chain (host-precomputed subkeys) + wave-
//    aggregated partition of row ids into list[B] in d_ws: n==0 rows (~40.6%)
//    from the FRONT (pure copy), n>0 rows from the BACK, n in low 5 bits.
//  * k2 rfm_main: 16-lane group per row, 2xfloat4 per tensor (proven round-3
//    geometry). Front groups = pure-copy waves (memory pipe); back groups =
//    hash+extract waves (VALU). CU-level overlap, no exec-mask waste.
// ---------------------------------------------------------------------------

#define DH __host__ __device__ __forceinline__

DH uint32_t rotl32(uint32_t v, uint32_t r) { return (v << r) | (v >> (32u - r)); }

// Threefry-2x32, 20 rounds (matches jax threefry2x32)
DH void tf2x32(uint32_t k0, uint32_t k1, uint32_t x0, uint32_t x1,
               uint32_t& o0, uint32_t& o1) {
  const uint32_t k2 = k0 ^ k1 ^ 0x1BD11BDAu;
  x0 += k0; x1 += k1;
  x0 += x1; x1 = rotl32(x1, 13); x1 ^= x0;
  x0 += x1; x1 = rotl32(x1, 15); x1 ^= x0;
  x0 += x1; x1 = rotl32(x1, 26); x1 ^= x0;
  x0 += x1; x1 = rotl32(x1,  6); x1 ^= x0;
  x0 += k1; x1 += k2 + 1u;
  x0 += x1; x1 = rotl32(x1, 17); x1 ^= x0;
  x0 += x1; x1 = rotl32(x1, 29); x1 ^= x0;
  x0 += x1; x1 = rotl32(x1, 16); x1 ^= x0;
  x0 += x1; x1 = rotl32(x1, 24); x1 ^= x0;
  x0 += k2; x1 += k0 + 2u;
  x0 += x1; x1 = rotl32(x1, 13); x1 ^= x0;
  x0 += x1; x1 = rotl32(x1, 15); x1 ^= x0;
  x0 += x1; x1 = rotl32(x1, 26); x1 ^= x0;
  x0 += x1; x1 = rotl32(x1,  6); x1 ^= x0;
  x0 += k0; x1 += k1 + 3u;
  x0 += x1; x1 = rotl32(x1, 17); x1 ^= x0;
  x0 += x1; x1 = rotl32(x1, 29); x1 ^= x0;
  x0 += x1; x1 = rotl32(x1, 16); x1 ^= x0;
  x0 += x1; x1 = rotl32(x1, 24); x1 ^= x0;
  x0 += k1; x1 += k2 + 4u;
  x0 += x1; x1 = rotl32(x1, 13); x1 ^= x0;
  x0 += x1; x1 = rotl32(x1, 15); x1 ^= x0;
  x0 += x1; x1 = rotl32(x1, 26); x1 ^= x0;
  x0 += x1; x1 = rotl32(x1,  6); x1 ^= x0;
  x0 += k2; x1 += k0 + 5u;
  o0 = x0; o1 = x1;
}

__device__ __forceinline__ float u01(uint32_t bits) {
  // jax.random.uniform: bitcast((bits>>9)|0x3f800000) - 1.0  (exact)
  return __uint_as_float((bits >> 9) | 0x3f800000u) - 1.0f;
}

struct PoisKeys { uint32_t s0[32]; uint32_t s1[32]; };

__global__ void zero_ctrs(uint32_t* __restrict__ ctrs) {
  if (threadIdx.x < 2) ctrs[threadIdx.x] = 0u;
}

// ---- k1: Poisson + partition. One lane per row.
// P(Poisson(2) >= 32) ~ 1e-25 -> 32 precomputed subkeys always suffice.
__global__ __launch_bounds__(256) void pois_part_kernel(
    uint32_t* __restrict__ list, uint32_t* __restrict__ ctrs, int B,
    PoisKeys pk) {
  const int row = (int)(blockIdx.x * 256u + threadIdx.x);
  const bool active = row < B;
  int n = 0;
  if (active) {
    float lp = 0.0f;
    int k = 0;
    for (int it = 0; it < 32; ++it) {
      if (lp <= -2.0f) break;
      uint32_t b0, b1;
      tf2x32(pk.s0[it], pk.s1[it], 0u, (uint32_t)row, b0, b1);
      ++k;
      // correctly-rounded f32 log via f64; f32 accumulation like reference
      lp += (float)log((double)u01(b0 ^ b1));
    }
    n = k - 1;
  }
  const int lane = (int)(threadIdx.x & 63u);
  const bool isZ = active && (n == 0);
  const bool isH = active && (n > 0);
  // strictly-below lane mask (lane 63: ~0>>1 = bits 0..62 — round-5 fix)
  const unsigned long long below = lane ? (~0ull >> (64 - lane)) : 0ull;
  const unsigned long long mz = __ballot(isZ);
  const unsigned long long mh = __ballot(isH);
  // wave-aggregated atomics: one atomicAdd per wave per class
  if (isZ) {
    const int cnt = __popcll(mz);
    const int lid = __popcll(mz & below);
    int basep = 0;
    if (lid == 0) basep = (int)atomicAdd(&ctrs[0], (uint32_t)cnt);
    basep = __shfl(basep, (int)(__ffsll((unsigned long long)mz) - 1));
    list[basep + lid] = (uint32_t)row;
  }
  if (isH) {
    const int cnt = __popcll(mh);
    const int lid = __popcll(mh & below);
    int basep = 0;
    if (lid == 0) basep = (int)atomicAdd(&ctrs[1], (uint32_t)cnt);
    basep = __shfl(basep, (int)(__ffsll((unsigned long long)mh) - 1));
    list[(B - 1) - (basep + lid)] = ((uint32_t)row << 5) | (uint32_t)min(n, 31);
  }
}

// ---- k2: main. 16-lane group per row; lane owns cols li*8 .. li*8+7.
__global__ __launch_bounds__(256) void rfm_main(
    const float* __restrict__ x, const float* __restrict__ mask,
    const uint32_t* __restrict__ list, const uint32_t* __restrict__ ctrs,
    float* __restrict__ out, int B, uint32_t ku0, uint32_t ku1) {
  const int G = (int)((blockIdx.x * 256u + threadIdx.x) >> 4);
  if (G >= B) return;
  const int li = (int)(threadIdx.x & 15u);
  const int zc = (int)ctrs[0];               // uniform, L2-hot

  int row, n = 0;
  bool hashp;
  if (G < zc) {
    row = (int)list[G];
    hashp = false;
  } else {
    const uint32_t e = list[(B - 1) - (G - zc)];
    row = (int)(e >> 5);
    n = (int)(e & 31u);
    hashp = true;
  }

  const size_t base = (size_t)row * 128u + (size_t)(li * 8);
  const size_t NF = (size_t)B * 128u;

  const float4 ma = *(const float4*)(mask + base);
  const float4 mb = *(const float4*)(mask + base + 4);
  const float4 xa = *(const float4*)(x + base);
  const float4 xb = *(const float4*)(x + base + 4);
  float mv[8] = {ma.x, ma.y, ma.z, ma.w, mb.x, mb.y, mb.z, mb.w};
  float xv[8] = {xa.x, xa.y, xa.z, xa.w, xb.x, xb.y, xb.z, xb.w};

  if (hashp) {
    // validity + scores: uniform(ku,(B,128)); bits = o0^o1(tf(ku; 0, idx))
    float s[8];
    int nv = 0;
    const uint32_t idx0 = (uint32_t)row * 128u + (uint32_t)(li * 8);
#pragma unroll
    for (int j = 0; j < 8; ++j) {
      uint32_t b0, b1;
      tf2x32(ku0, ku1, 0u, idx0 + (uint32_t)j, b0, b1);
      const bool valid = mv[j] > 0.5f;
      s[j] = valid ? u01(b0 ^ b1) : -1.0f;
      nv += valid ? 1 : 0;
    }
#pragma unroll
    for (int off = 8; off; off >>= 1) nv += __shfl_xor(nv, off);  // group sum

    n = (nv > 1) ? min(n, nv - 1) : 0;

    // drop the n highest-scoring positions (ties -> lower column index,
    // matching stable argsort; top-n always valid since n <= nv-1)
    uint32_t dropbits = 0u;
    for (int t = 0; t < n; ++t) {
      float bs = s[0];
      int bj = 0;
#pragma unroll
      for (int j = 1; j < 8; ++j) {
        if (s[j] > bs) { bs = s[j]; bj = j; }  // strict >: lowest j wins ties
      }
      int bc = (li << 3) + bj;
#pragma unroll
      for (int off = 8; off; off >>= 1) {      // group butterfly argmax
        const float os = __shfl_xor(bs, off);
        const int   oc = __shfl_xor(bc, off);
        if (os > bs || (os == bs && oc < bc)) { bs = os; bc = oc; }
      }
      const bool own = (bc >> 3) == li;
      const int  lj  = bc & 7;
#pragma unroll
      for (int j = 0; j < 8; ++j) {            // static indices only
        if (own && lj == j) { s[j] = -2.0f; dropbits |= (1u << j); }
      }
    }
#pragma unroll
    for (int j = 0; j < 8; ++j) {
      if ((dropbits >> j) & 1u) { xv[j] = 0.0f; mv[j] = 0.0f; }
    }
  }

  float4 o;
  o.x = xv[0]; o.y = xv[1]; o.z = xv[2]; o.w = xv[3];
  *(float4*)(out + base) = o;
  o.x = xv[4]; o.y = xv[5]; o.z = xv[6]; o.w = xv[7];
  *(float4*)(out + base + 4) = o;
  o.x = mv[0]; o.y = mv[1]; o.z = mv[2]; o.w = mv[3];
  *(float4*)(out + NF + base) = o;
  o.x = mv[4]; o.y = mv[5]; o.z = mv[6]; o.w = mv[7];
  *(float4*)(out + NF + base + 4) = o;
}

// ---- fallback (ws too small): round-3 fused kernel, no scratch needed.
__global__ __launch_bounds__(256) void rfm_fused(
    const float* __restrict__ x, const float* __restrict__ mask,
    float* __restrict__ out, int B,
    uint32_t ku0, uint32_t ku1, PoisKeys pk) {
  const int tid = (int)threadIdx.x;
  const int row = (int)blockIdx.x * 16 + (tid >> 4);
  if (row >= B) return;
  const int li = tid & 15;
  const int gb = (tid & 63) & 48;
  const size_t base = (size_t)row * 128u + (size_t)(li * 8);
  const size_t NF = (size_t)B * 128u;

  const float4 ma = *(const float4*)(mask + base);
  const float4 mb = *(const float4*)(mask + base + 4);
  const float4 xa = *(const float4*)(x + base);
  const float4 xb = *(const float4*)(x + base + 4);

  float lg;
  {
    uint32_t b0, b1;
    tf2x32(pk.s0[li], pk.s1[li], 0u, (uint32_t)row, b0, b1);
    lg = (float)log((double)u01(b0 ^ b1));
  }
  float lp = 0.0f;
  int k = 0;
#pragma unroll
  for (int j = 0; j < 8; ++j) {
    const float lj = __shfl(lg, gb + j);
    k += (lp > -2.0f) ? 1 : 0;
    lp += lj;
  }
  if (lp > -2.0f) {
#pragma unroll
    for (int j = 8; j < 16; ++j) {
      const float lj = __shfl(lg, gb + j);
      k += (lp > -2.0f) ? 1 : 0;
      lp += lj;
    }
    if (lp > -2.0f) {
      uint32_t c0, c1;
      const int i2 = 16 + (li & 7);
      tf2x32(pk.s0[i2], pk.s1[i2], 0u, (uint32_t)row, c0, c1);
      const float lg2 = (float)log((double)u01(c0 ^ c1));
#pragma unroll
      for (int j = 0; j < 8; ++j) {
        const float lj = __shfl(lg2, gb + j);
        k += (lp > -2.0f) ? 1 : 0;
        lp += lj;
      }
    }
  }
  int n = k - 1;

  float mv[8] = {ma.x, ma.y, ma.z, ma.w, mb.x, mb.y, mb.z, mb.w};
  float s[8];
  int nv = 0;
  const uint32_t idx0 = (uint32_t)row * 128u + (uint32_t)(li * 8);
#pragma unroll
  for (int j = 0; j < 8; ++j) {
    uint32_t b0, b1;
    tf2x32(ku0, ku1, 0u, idx0 + (uint32_t)j, b0, b1);
    const bool valid = mv[j] > 0.5f;
    s[j] = valid ? u01(b0 ^ b1) : -1.0f;
    nv += valid ? 1 : 0;
  }
#pragma unroll
  for (int off = 8; off; off >>= 1) nv += __shfl_xor(nv, off);
  n = (nv > 1) ? min(n, nv - 1) : 0;

  uint32_t dropbits = 0u;
  for (int t = 0; t < n; ++t) {
    float bs = s[0];
    int bj = 0;
#pragma unroll
    for (int j = 1; j < 8; ++j) {
      if (s[j] > bs) { bs = s[j]; bj = j; }
    }
    int bc = (li << 3) + bj;
#pragma unroll
    for (int off = 8; off; off >>= 1) {
      const float os = __shfl_xor(bs, off);
      const int   oc = __shfl_xor(bc, off);
      if (os > bs || (os == bs && oc < bc)) { bs = os; bc = oc; }
    }
    const bool own = (bc >> 3) == li;
    const int  lj  = bc & 7;
#pragma unroll
    for (int j = 0; j < 8; ++j) {
      if (own && lj == j) { s[j] = -2.0f; dropbits |= (1u << j); }
    }
  }

  float xv[8] = {xa.x, xa.y, xa.z, xa.w, xb.x, xb.y, xb.z, xb.w};
#pragma unroll
  for (int j = 0; j < 8; ++j) {
    if ((dropbits >> j) & 1u) { xv[j] = 0.0f; mv[j] = 0.0f; }
  }
  float4 o;
  o.x = xv[0]; o.y = xv[1]; o.z = xv[2]; o.w = xv[3];
  *(float4*)(out + base) = o;
  o.x = xv[4]; o.y = xv[5]; o.z = xv[6]; o.w = xv[7];
  *(float4*)(out + base + 4) = o;
  o.x = mv[0]; o.y = mv[1]; o.z = mv[2]; o.w = mv[3];
  *(float4*)(out + NF + base) = o;
  o.x = mv[4]; o.y = mv[5]; o.z = mv[6]; o.w = mv[7];
  *(float4*)(out + NF + base + 4) = o;
}

extern "C" void kernel_launch(void* const* d_in, const int* in_sizes, int n_in,
                              void* d_out, int out_size, void* d_ws, size_t ws_size,
                              hipStream_t stream) {
  const float* x    = (const float*)d_in[0];
  const float* mask = (const float*)d_in[1];
  float* out = (float*)d_out;

  const int B = in_sizes[0] / 128;  // 500000

  // kp, ku = jax.random.split(jax.random.key(42)); key data = (0,42)
  // partitionable/foldlike: key[i] = full threefry output at counter (0, i)
  uint32_t kp0, kp1, ku0, ku1;
  tf2x32(0u, 42u, 0u, 0u, kp0, kp1);
  tf2x32(0u, 42u, 0u, 1u, ku0, ku1);

  // Host-precompute the Poisson rng-split chain (row-independent):
  // per iter: subkey = tf(rng; 0,1); rng = tf(rng; 0,0)
  PoisKeys pk;
  {
    uint32_t r0 = kp0, r1 = kp1;
    for (int it = 0; it < 32; ++it) {
      uint32_t s0, s1, t0, t1;
      tf2x32(r0, r1, 0u, 1u, s0, s1);
      tf2x32(r0, r1, 0u, 0u, t0, t1);
      pk.s0[it] = s0; pk.s1[it] = s1;
      r0 = t0; r1 = t1;
    }
  }

  const size_t wsNeeded = (size_t)B * 4u + 8u;
  if (ws_size < wsNeeded) {
    // fallback: fused single kernel (round-3 structure, 237 us)
    rfm_fused<<<(B + 15) / 16, 256, 0, stream>>>(x, mask, out, B, ku0, ku1, pk);
    return;
  }

  uint32_t* list = (uint32_t*)d_ws;
  uint32_t* ctrs = (uint32_t*)((char*)d_ws + (size_t)B * 4u);
  zero_ctrs<<<1, 64, 0, stream>>>(ctrs);
  pois_part_kernel<<<(B + 255) / 256, 256, 0, stream>>>(list, ctrs, B, pk);
  rfm_main<<<(B + 15) / 16, 256, 0, stream>>>(x, mask, list, ctrs, out, B,
                                              ku0, ku1);
}

// Round 7
// 249.313 us; speedup vs baseline: 1.5964x; 1.5964x over previous
//
#include <hip/hip_runtime.h>
#include <cstdint>
#include <math.h>

// ---------------------------------------------------------------------------
// Bit-exact replication of jax.random with threefry_partitionable=True:
//   split(key)      -> key[i] = threefry(key; hi=0, lo=i)  (foldlike)
//   random_bits 32b -> o0 ^ o1 of threefry(key; hi=0, lo=flat_idx)
//   kp, ku = split(key(42)); key data = (0,42)
//   n_raw = poisson_knuth(kp, 2.0)[row]           (data-INDEPENDENT)
//   n = where(nv>1, min(n_raw, nv-1), 0)
//   scores = where(valid, uniform(ku,(B,128)), -1); drop top-n (stable ties)
//
// Round-6 post-mortem: partition/indirection scatters the memory stream and
// destroys DRAM locality (237 -> 398 us). Round 7 keeps SEQUENTIAL row order
// and the proven 16-lane-group float4 geometry, and attacks OVERLAP instead:
//  * k1 pois_n: n_raw -> u8[B] in row order (chain precomputed on host).
//  * k2 rfm_main: persistent grid-stride; software pipeline (prefetch next
//    row's mask+n while hashing current row; x loads issued before hash).
// ---------------------------------------------------------------------------

#define DH __host__ __device__ __forceinline__

DH uint32_t rotl32(uint32_t v, uint32_t r) { return (v << r) | (v >> (32u - r)); }

// Threefry-2x32, 20 rounds (matches jax threefry2x32)
DH void tf2x32(uint32_t k0, uint32_t k1, uint32_t x0, uint32_t x1,
               uint32_t& o0, uint32_t& o1) {
  const uint32_t k2 = k0 ^ k1 ^ 0x1BD11BDAu;
  x0 += k0; x1 += k1;
  x0 += x1; x1 = rotl32(x1, 13); x1 ^= x0;
  x0 += x1; x1 = rotl32(x1, 15); x1 ^= x0;
  x0 += x1; x1 = rotl32(x1, 26); x1 ^= x0;
  x0 += x1; x1 = rotl32(x1,  6); x1 ^= x0;
  x0 += k1; x1 += k2 + 1u;
  x0 += x1; x1 = rotl32(x1, 17); x1 ^= x0;
  x0 += x1; x1 = rotl32(x1, 29); x1 ^= x0;
  x0 += x1; x1 = rotl32(x1, 16); x1 ^= x0;
  x0 += x1; x1 = rotl32(x1, 24); x1 ^= x0;
  x0 += k2; x1 += k0 + 2u;
  x0 += x1; x1 = rotl32(x1, 13); x1 ^= x0;
  x0 += x1; x1 = rotl32(x1, 15); x1 ^= x0;
  x0 += x1; x1 = rotl32(x1, 26); x1 ^= x0;
  x0 += x1; x1 = rotl32(x1,  6); x1 ^= x0;
  x0 += k0; x1 += k1 + 3u;
  x0 += x1; x1 = rotl32(x1, 17); x1 ^= x0;
  x0 += x1; x1 = rotl32(x1, 29); x1 ^= x0;
  x0 += x1; x1 = rotl32(x1, 16); x1 ^= x0;
  x0 += x1; x1 = rotl32(x1, 24); x1 ^= x0;
  x0 += k1; x1 += k2 + 4u;
  x0 += x1; x1 = rotl32(x1, 13); x1 ^= x0;
  x0 += x1; x1 = rotl32(x1, 15); x1 ^= x0;
  x0 += x1; x1 = rotl32(x1, 26); x1 ^= x0;
  x0 += x1; x1 = rotl32(x1,  6); x1 ^= x0;
  x0 += k2; x1 += k0 + 5u;
  o0 = x0; o1 = x1;
}

__device__ __forceinline__ float u01(uint32_t bits) {
  // jax.random.uniform: bitcast((bits>>9)|0x3f800000) - 1.0  (exact)
  return __uint_as_float((bits >> 9) | 0x3f800000u) - 1.0f;
}

struct PoisKeys { uint32_t s0[32]; uint32_t s1[32]; };

// ---- k1: Poisson n_raw -> u8[B], one lane per row, ROW ORDER (no scatter).
// P(Poisson(2) >= 32) ~ 1e-25 -> 32 precomputed subkeys always suffice.
__global__ __launch_bounds__(256) void pois_n_kernel(
    uint8_t* __restrict__ nout, int B, PoisKeys pk) {
  const int row = (int)(blockIdx.x * 256u + threadIdx.x);
  if (row >= B) return;
  float lp = 0.0f;
  int k = 0;
  for (int it = 0; it < 32; ++it) {
    if (lp <= -2.0f) break;
    uint32_t b0, b1;
    tf2x32(pk.s0[it], pk.s1[it], 0u, (uint32_t)row, b0, b1);
    ++k;
    // correctly-rounded f32 log via f64; f32 accumulation like the reference
    lp += (float)log((double)u01(b0 ^ b1));
  }
  nout[row] = (uint8_t)(k - 1);
}

// ---- k2: main. Persistent grid-stride; 16-lane group per row; lane li owns
// cols li*8 .. li*8+7 (2x float4 per tensor). Software pipeline: next row's
// mask+n prefetched during current row's hash; x issued before hash.
__global__ __launch_bounds__(256) void rfm_main(
    const float* __restrict__ x, const float* __restrict__ mask,
    const uint8_t* __restrict__ nraw, float* __restrict__ out,
    int B, int G, uint32_t ku0, uint32_t ku1) {
  const int tid = (int)threadIdx.x;
  const int li  = tid & 15;
  const int g0  = (int)(blockIdx.x * 16u) + (tid >> 4);
  if (g0 >= B) return;
  const size_t NF = (size_t)B * 128u;
  const size_t lo = (size_t)(li * 8);

  // prologue: current row's mask + n
  {
  }
  size_t pbase = (size_t)g0 * 128u + lo;
  float4 cma = *(const float4*)(mask + pbase);
  float4 cmb = *(const float4*)(mask + pbase + 4);
  int cn = (int)nraw[g0];

  for (int r = g0; r < B; ) {
    const size_t base = (size_t)r * 128u + lo;
    // current row x: issue now, consumed after hashing (latency hidden)
    const float4 xa = *(const float4*)(x + base);
    const float4 xb = *(const float4*)(x + base + 4);
    // next row mask + n: prefetch (consumed next iteration)
    const int rn = r + G;
    float4 nma, nmb;
    int nn = 0;
    if (rn < B) {
      const size_t nb = (size_t)rn * 128u + lo;
      nma = *(const float4*)(mask + nb);
      nmb = *(const float4*)(mask + nb + 4);
      nn = (int)nraw[rn];
    } else {
      nma = cma; nmb = cmb;
    }

    float mv[8] = {cma.x, cma.y, cma.z, cma.w, cmb.x, cmb.y, cmb.z, cmb.w};
    uint32_t dropbits = 0u;

    if (__any(cn > 0)) {            // skip only when whole wave is n==0 (~3%)
      // scores: uniform(ku,(B,128)); bits = o0^o1 of tf(ku; 0, flat_idx)
      float s[8];
      int nv = 0;
      const uint32_t idx0 = (uint32_t)r * 128u + (uint32_t)(li * 8);
#pragma unroll
      for (int j = 0; j < 8; ++j) {
        uint32_t b0, b1;
        tf2x32(ku0, ku1, 0u, idx0 + (uint32_t)j, b0, b1);
        const bool valid = mv[j] > 0.5f;
        s[j] = valid ? u01(b0 ^ b1) : -1.0f;
        nv += valid ? 1 : 0;
      }
#pragma unroll
      for (int off = 8; off; off >>= 1) nv += __shfl_xor(nv, off);  // group sum

      const int nd = (nv > 1) ? min(cn, nv - 1) : 0;

      // drop the nd highest-scoring positions (ties -> lower column index,
      // matching stable argsort; top-n always valid since nd <= nv-1)
      for (int t = 0; t < nd; ++t) {
        float bs = s[0];
        int bj = 0;
#pragma unroll
        for (int j = 1; j < 8; ++j) {
          if (s[j] > bs) { bs = s[j]; bj = j; }  // strict >: lowest j ties
        }
        int bc = (li << 3) + bj;
#pragma unroll
        for (int off = 8; off; off >>= 1) {      // group butterfly argmax
          const float os = __shfl_xor(bs, off);
          const int   oc = __shfl_xor(bc, off);
          if (os > bs || (os == bs && oc < bc)) { bs = os; bc = oc; }
        }
        const bool own = (bc >> 3) == li;
        const int  lj  = bc & 7;
#pragma unroll
        for (int j = 0; j < 8; ++j) {            // static indices only
          if (own && lj == j) { s[j] = -2.0f; dropbits |= (1u << j); }
        }
      }
    }

    float xv[8] = {xa.x, xa.y, xa.z, xa.w, xb.x, xb.y, xb.z, xb.w};
#pragma unroll
    for (int j = 0; j < 8; ++j) {
      if ((dropbits >> j) & 1u) { xv[j] = 0.0f; mv[j] = 0.0f; }
    }
    float4 o;
    o.x = xv[0]; o.y = xv[1]; o.z = xv[2]; o.w = xv[3];
    *(float4*)(out + base) = o;
    o.x = xv[4]; o.y = xv[5]; o.z = xv[6]; o.w = xv[7];
    *(float4*)(out + base + 4) = o;
    o.x = mv[0]; o.y = mv[1]; o.z = mv[2]; o.w = mv[3];
    *(float4*)(out + NF + base) = o;
    o.x = mv[4]; o.y = mv[5]; o.z = mv[6]; o.w = mv[7];
    *(float4*)(out + NF + base + 4) = o;

    // rotate pipeline
    r = rn; cma = nma; cmb = nmb; cn = nn;
  }
}

// ---- fallback (ws too small): round-3 fused kernel, no scratch needed.
__global__ __launch_bounds__(256) void rfm_fused(
    const float* __restrict__ x, const float* __restrict__ mask,
    float* __restrict__ out, int B,
    uint32_t ku0, uint32_t ku1, PoisKeys pk) {
  const int tid = (int)threadIdx.x;
  const int row = (int)blockIdx.x * 16 + (tid >> 4);
  if (row >= B) return;
  const int li = tid & 15;
  const int gb = (tid & 63) & 48;
  const size_t base = (size_t)row * 128u + (size_t)(li * 8);
  const size_t NF = (size_t)B * 128u;

  const float4 ma = *(const float4*)(mask + base);
  const float4 mb = *(const float4*)(mask + base + 4);
  const float4 xa = *(const float4*)(x + base);
  const float4 xb = *(const float4*)(x + base + 4);

  float lg;
  {
    uint32_t b0, b1;
    tf2x32(pk.s0[li], pk.s1[li], 0u, (uint32_t)row, b0, b1);
    lg = (float)log((double)u01(b0 ^ b1));
  }
  float lp = 0.0f;
  int k = 0;
#pragma unroll
  for (int j = 0; j < 8; ++j) {
    const float lj = __shfl(lg, gb + j);
    k += (lp > -2.0f) ? 1 : 0;
    lp += lj;
  }
  if (lp > -2.0f) {
#pragma unroll
    for (int j = 8; j < 16; ++j) {
      const float lj = __shfl(lg, gb + j);
      k += (lp > -2.0f) ? 1 : 0;
      lp += lj;
    }
    if (lp > -2.0f) {
      uint32_t c0, c1;
      const int i2 = 16 + (li & 7);
      tf2x32(pk.s0[i2], pk.s1[i2], 0u, (uint32_t)row, c0, c1);
      const float lg2 = (float)log((double)u01(c0 ^ c1));
#pragma unroll
      for (int j = 0; j < 8; ++j) {
        const float lj = __shfl(lg2, gb + j);
        k += (lp > -2.0f) ? 1 : 0;
        lp += lj;
      }
    }
  }
  int n = k - 1;

  float mv[8] = {ma.x, ma.y, ma.z, ma.w, mb.x, mb.y, mb.z, mb.w};
  float s[8];
  int nv = 0;
  const uint32_t idx0 = (uint32_t)row * 128u + (uint32_t)(li * 8);
#pragma unroll
  for (int j = 0; j < 8; ++j) {
    uint32_t b0, b1;
    tf2x32(ku0, ku1, 0u, idx0 + (uint32_t)j, b0, b1);
    const bool valid = mv[j] > 0.5f;
    s[j] = valid ? u01(b0 ^ b1) : -1.0f;
    nv += valid ? 1 : 0;
  }
#pragma unroll
  for (int off = 8; off; off >>= 1) nv += __shfl_xor(nv, off);
  n = (nv > 1) ? min(n, nv - 1) : 0;

  uint32_t dropbits = 0u;
  for (int t = 0; t < n; ++t) {
    float bs = s[0];
    int bj = 0;
#pragma unroll
    for (int j = 1; j < 8; ++j) {
      if (s[j] > bs) { bs = s[j]; bj = j; }
    }
    int bc = (li << 3) + bj;
#pragma unroll
    for (int off = 8; off; off >>= 1) {
      const float os = __shfl_xor(bs, off);
      const int   oc = __shfl_xor(bc, off);
      if (os > bs || (os == bs && oc < bc)) { bs = os; bc = oc; }
    }
    const bool own = (bc >> 3) == li;
    const int  lj  = bc & 7;
#pragma unroll
    for (int j = 0; j < 8; ++j) {
      if (own && lj == j) { s[j] = -2.0f; dropbits |= (1u << j); }
    }
  }

  float xv[8] = {xa.x, xa.y, xa.z, xa.w, xb.x, xb.y, xb.z, xb.w};
#pragma unroll
  for (int j = 0; j < 8; ++j) {
    if ((dropbits >> j) & 1u) { xv[j] = 0.0f; mv[j] = 0.0f; }
  }
  float4 o;
  o.x = xv[0]; o.y = xv[1]; o.z = xv[2]; o.w = xv[3];
  *(float4*)(out + base) = o;
  o.x = xv[4]; o.y = xv[5]; o.z = xv[6]; o.w = xv[7];
  *(float4*)(out + base + 4) = o;
  o.x = mv[0]; o.y = mv[1]; o.z = mv[2]; o.w = mv[3];
  *(float4*)(out + NF + base) = o;
  o.x = mv[4]; o.y = mv[5]; o.z = mv[6]; o.w = mv[7];
  *(float4*)(out + NF + base + 4) = o;
}

extern "C" void kernel_launch(void* const* d_in, const int* in_sizes, int n_in,
                              void* d_out, int out_size, void* d_ws, size_t ws_size,
                              hipStream_t stream) {
  const float* x    = (const float*)d_in[0];
  const float* mask = (const float*)d_in[1];
  float* out = (float*)d_out;

  const int B = in_sizes[0] / 128;  // 500000

  // kp, ku = jax.random.split(jax.random.key(42)); key data = (0,42)
  // partitionable/foldlike: key[i] = full threefry output at counter (0, i)
  uint32_t kp0, kp1, ku0, ku1;
  tf2x32(0u, 42u, 0u, 0u, kp0, kp1);
  tf2x32(0u, 42u, 0u, 1u, ku0, ku1);

  // Host-precompute the Poisson rng-split chain (row-independent):
  // per iter: subkey = tf(rng; 0,1); rng = tf(rng; 0,0)
  PoisKeys pk;
  {
    uint32_t r0 = kp0, r1 = kp1;
    for (int it = 0; it < 32; ++it) {
      uint32_t s0, s1, t0, t1;
      tf2x32(r0, r1, 0u, 1u, s0, s1);
      tf2x32(r0, r1, 0u, 0u, t0, t1);
      pk.s0[it] = s0; pk.s1[it] = s1;
      r0 = t0; r1 = t1;
    }
  }

  if (ws_size < (size_t)B) {
    // fallback: fused single kernel (round-3 structure, 237 us)
    rfm_fused<<<(B + 15) / 16, 256, 0, stream>>>(x, mask, out, B, ku0, ku1, pk);
    return;
  }

  uint8_t* nraw = (uint8_t*)d_ws;
  pois_n_kernel<<<(B + 255) / 256, 256, 0, stream>>>(nraw, B, pk);

  // persistent grid: 2048 blocks = 8 blocks/CU on 256 CUs; grid-stride rows
  int blocks = (B + 15) / 16;
  if (blocks > 2048) blocks = 2048;
  const int G = blocks * 16;        // total groups = row stride
  rfm_main<<<blocks, 256, 0, stream>>>(x, mask, nraw, out, B, G, ku0, ku1);
}

// Round 8
// 229.870 us; speedup vs baseline: 1.7315x; 1.0846x over previous
//
#include <hip/hip_runtime.h>
#include <cstdint>
#include <math.h>

// ---------------------------------------------------------------------------
// Bit-exact replication of jax.random with threefry_partitionable=True:
//   split(key)      -> key[i] = threefry(key; hi=0, lo=i)  (foldlike)
//   random_bits 32b -> o0 ^ o1 of threefry(key; hi=0, lo=flat_idx)
//   kp, ku = split(key(42)); key data = (0,42)
//   n_raw = poisson_knuth(kp, 2.0)[row]           (data-INDEPENDENT)
//   n = where(nv>1, min(n_raw, nv-1), 0)
//   scores = where(valid, uniform(ku,(B,128)), -1); drop top-n (stable ties)
//
// Round 4-7 synthesis: the kernel is VALU-bound (round-2 PMC: VALUBusy 63%,
// ~210us VALU vs ~120us memory floor); 40.6% of rows (n_raw==0) need ZERO
// hashing, but a GLOBAL partition scatters DRAM access (round 6: +160us).
// Fix: partition by class WITHIN each 64-consecutive-row block window:
//  * k1 pois_n: n_raw -> u8[B] (host-precomputed subkey chain; verified).
//  * k2 rfm_main: 1024-thr block = 64 groups x 16 lanes owns 64 consecutive
//    rows. Wave 0 ballot-partitions row indices in LDS (hash rows first),
//    one barrier, then groups run class-pure waves: copy waves stream the
//    memory pipe while hash waves chew VALU (CU-level overlap).
//  * Ranking by monotone integer key (bits>>9)+1 (invalid=0): same order and
//    ties as the float scores, fewer VALU ops.
// ---------------------------------------------------------------------------

#define DH __host__ __device__ __forceinline__

DH uint32_t rotl32(uint32_t v, uint32_t r) { return (v << r) | (v >> (32u - r)); }

// Threefry-2x32, 20 rounds (matches jax threefry2x32)
DH void tf2x32(uint32_t k0, uint32_t k1, uint32_t x0, uint32_t x1,
               uint32_t& o0, uint32_t& o1) {
  const uint32_t k2 = k0 ^ k1 ^ 0x1BD11BDAu;
  x0 += k0; x1 += k1;
  x0 += x1; x1 = rotl32(x1, 13); x1 ^= x0;
  x0 += x1; x1 = rotl32(x1, 15); x1 ^= x0;
  x0 += x1; x1 = rotl32(x1, 26); x1 ^= x0;
  x0 += x1; x1 = rotl32(x1,  6); x1 ^= x0;
  x0 += k1; x1 += k2 + 1u;
  x0 += x1; x1 = rotl32(x1, 17); x1 ^= x0;
  x0 += x1; x1 = rotl32(x1, 29); x1 ^= x0;
  x0 += x1; x1 = rotl32(x1, 16); x1 ^= x0;
  x0 += x1; x1 = rotl32(x1, 24); x1 ^= x0;
  x0 += k2; x1 += k0 + 2u;
  x0 += x1; x1 = rotl32(x1, 13); x1 ^= x0;
  x0 += x1; x1 = rotl32(x1, 15); x1 ^= x0;
  x0 += x1; x1 = rotl32(x1, 26); x1 ^= x0;
  x0 += x1; x1 = rotl32(x1,  6); x1 ^= x0;
  x0 += k0; x1 += k1 + 3u;
  x0 += x1; x1 = rotl32(x1, 17); x1 ^= x0;
  x0 += x1; x1 = rotl32(x1, 29); x1 ^= x0;
  x0 += x1; x1 = rotl32(x1, 16); x1 ^= x0;
  x0 += x1; x1 = rotl32(x1, 24); x1 ^= x0;
  x0 += k1; x1 += k2 + 4u;
  x0 += x1; x1 = rotl32(x1, 13); x1 ^= x0;
  x0 += x1; x1 = rotl32(x1, 15); x1 ^= x0;
  x0 += x1; x1 = rotl32(x1, 26); x1 ^= x0;
  x0 += x1; x1 = rotl32(x1,  6); x1 ^= x0;
  x0 += k2; x1 += k0 + 5u;
  o0 = x0; o1 = x1;
}

__device__ __forceinline__ float u01(uint32_t bits) {
  // jax.random.uniform: bitcast((bits>>9)|0x3f800000) - 1.0  (exact)
  return __uint_as_float((bits >> 9) | 0x3f800000u) - 1.0f;
}

struct PoisKeys { uint32_t s0[32]; uint32_t s1[32]; };

// ---- k1: Poisson n_raw -> u8[B], one lane per row, ROW ORDER.
// P(Poisson(2) >= 32) ~ 1e-25 -> 32 precomputed subkeys always suffice.
// (Bit-exact verified in rounds 4/6/7.)
__global__ __launch_bounds__(256) void pois_n_kernel(
    uint8_t* __restrict__ nout, int B, PoisKeys pk) {
  const int row = (int)(blockIdx.x * 256u + threadIdx.x);
  if (row >= B) return;
  float lp = 0.0f;
  int k = 0;
  for (int it = 0; it < 32; ++it) {
    if (lp <= -2.0f) break;
    uint32_t b0, b1;
    tf2x32(pk.s0[it], pk.s1[it], 0u, (uint32_t)row, b0, b1);
    ++k;
    // correctly-rounded f32 log via f64; f32 accumulation like the reference
    lp += (float)log((double)u01(b0 ^ b1));
  }
  nout[row] = (uint8_t)(k - 1);
}

// ---- k2: main. Block = 1024 threads = 64 groups x 16 lanes, 64 consecutive
// rows. Wave 0 partitions rows by class (n>0 first) into s_perm; groups then
// run class-pure waves. Lane li owns cols li*8 .. li*8+7 (2x float4/tensor).
__global__ __launch_bounds__(1024) void rfm_main(
    const float* __restrict__ x, const float* __restrict__ mask,
    const uint8_t* __restrict__ nraw, float* __restrict__ out,
    int B, uint32_t ku0, uint32_t ku1) {
  __shared__ uint8_t s_n[64];
  __shared__ uint8_t s_perm[64];
  const int tid = (int)threadIdx.x;
  const int rowBase = (int)(blockIdx.x * 64u);
  const int nvalid = min(64, B - rowBase);

  if (tid < 64) {                    // exactly wave 0
    const bool vr = tid < nvalid;
    const int n = vr ? (int)nraw[rowBase + tid] : 0;
    s_n[tid] = (uint8_t)n;
    const bool cls = vr && (n > 0);
    const unsigned long long mh  = __ballot(cls);
    const unsigned long long mvr = __ballot(vr);
    // strictly-below lane mask (round-5 fix: lane 63 -> bits 0..62)
    const unsigned long long below = tid ? (~0ull >> (64 - tid)) : 0ull;
    const int npos = __popcll(mh);
    if (vr) {
      const int slot = cls ? __popcll(mh & below)
                           : npos + __popcll(mvr & (~mh) & below);
      s_perm[slot] = (uint8_t)tid;
    }
  }
  __syncthreads();

  const int g = tid >> 4;
  if (g >= nvalid) return;
  const int li = tid & 15;
  const int j = (int)s_perm[g];
  const int row = rowBase + j;
  int n = (int)s_n[j];               // group-uniform; class-pure per wave

  const size_t base = (size_t)row * 128u + (size_t)(li * 8);
  const size_t NF = (size_t)B * 128u;

  const float4 ma = *(const float4*)(mask + base);
  const float4 mb = *(const float4*)(mask + base + 4);
  const float4 xa = *(const float4*)(x + base);
  const float4 xb = *(const float4*)(x + base + 4);
  float mv[8] = {ma.x, ma.y, ma.z, ma.w, mb.x, mb.y, mb.z, mb.w};
  float xv[8] = {xa.x, xa.y, xa.z, xa.w, xb.x, xb.y, xb.z, xb.w};

  if (n > 0) {
    // integer ranking key: valid -> (bits>>9)+1 in [1, 2^23], invalid -> 0.
    // Strictly monotone in the reference's float score; identical ties.
    uint32_t s[8];
    int nv = 0;
    const uint32_t idx0 = (uint32_t)row * 128u + (uint32_t)(li * 8);
#pragma unroll
    for (int jj = 0; jj < 8; ++jj) {
      uint32_t b0, b1;
      tf2x32(ku0, ku1, 0u, idx0 + (uint32_t)jj, b0, b1);
      const bool valid = mv[jj] > 0.5f;
      s[jj] = valid ? (((b0 ^ b1) >> 9) + 1u) : 0u;
      nv += valid ? 1 : 0;
    }
#pragma unroll
    for (int off = 8; off; off >>= 1) nv += __shfl_xor(nv, off);  // group sum

    n = (nv > 1) ? min(n, nv - 1) : 0;

    // drop the n highest-key positions (ties -> lower column index, matching
    // stable argsort; top-n always valid since n <= nv-1)
    uint32_t dropbits = 0u;
    for (int t = 0; t < n; ++t) {
      uint32_t bs = s[0];
      int bj = 0;
#pragma unroll
      for (int jj = 1; jj < 8; ++jj) {
        if (s[jj] > bs) { bs = s[jj]; bj = jj; }  // strict >: lowest j ties
      }
      int bc = (li << 3) + bj;
#pragma unroll
      for (int off = 8; off; off >>= 1) {         // group butterfly argmax
        const uint32_t os = __shfl_xor(bs, off);
        const int      oc = __shfl_xor(bc, off);
        if (os > bs || (os == bs && oc < bc)) { bs = os; bc = oc; }
      }
      const bool own = (bc >> 3) == li;
      const int  lj  = bc & 7;
#pragma unroll
      for (int jj = 0; jj < 8; ++jj) {            // static indices only
        if (own && lj == jj) { s[jj] = 0u; dropbits |= (1u << jj); }
      }
    }
#pragma unroll
    for (int jj = 0; jj < 8; ++jj) {
      if ((dropbits >> jj) & 1u) { xv[jj] = 0.0f; mv[jj] = 0.0f; }
    }
  }

  float4 o;
  o.x = xv[0]; o.y = xv[1]; o.z = xv[2]; o.w = xv[3];
  *(float4*)(out + base) = o;
  o.x = xv[4]; o.y = xv[5]; o.z = xv[6]; o.w = xv[7];
  *(float4*)(out + base + 4) = o;
  o.x = mv[0]; o.y = mv[1]; o.z = mv[2]; o.w = mv[3];
  *(float4*)(out + NF + base) = o;
  o.x = mv[4]; o.y = mv[5]; o.z = mv[6]; o.w = mv[7];
  *(float4*)(out + NF + base + 4) = o;
}

// ---- fallback (ws too small): round-3 fused kernel, no scratch needed.
__global__ __launch_bounds__(256) void rfm_fused(
    const float* __restrict__ x, const float* __restrict__ mask,
    float* __restrict__ out, int B,
    uint32_t ku0, uint32_t ku1, PoisKeys pk) {
  const int tid = (int)threadIdx.x;
  const int row = (int)blockIdx.x * 16 + (tid >> 4);
  if (row >= B) return;
  const int li = tid & 15;
  const int gb = (tid & 63) & 48;
  const size_t base = (size_t)row * 128u + (size_t)(li * 8);
  const size_t NF = (size_t)B * 128u;

  const float4 ma = *(const float4*)(mask + base);
  const float4 mb = *(const float4*)(mask + base + 4);
  const float4 xa = *(const float4*)(x + base);
  const float4 xb = *(const float4*)(x + base + 4);

  float lg;
  {
    uint32_t b0, b1;
    tf2x32(pk.s0[li], pk.s1[li], 0u, (uint32_t)row, b0, b1);
    lg = (float)log((double)u01(b0 ^ b1));
  }
  float lp = 0.0f;
  int k = 0;
#pragma unroll
  for (int j = 0; j < 8; ++j) {
    const float lj = __shfl(lg, gb + j);
    k += (lp > -2.0f) ? 1 : 0;
    lp += lj;
  }
  if (lp > -2.0f) {
#pragma unroll
    for (int j = 8; j < 16; ++j) {
      const float lj = __shfl(lg, gb + j);
      k += (lp > -2.0f) ? 1 : 0;
      lp += lj;
    }
    if (lp > -2.0f) {
      uint32_t c0, c1;
      const int i2 = 16 + (li & 7);
      tf2x32(pk.s0[i2], pk.s1[i2], 0u, (uint32_t)row, c0, c1);
      const float lg2 = (float)log((double)u01(c0 ^ c1));
#pragma unroll
      for (int j = 0; j < 8; ++j) {
        const float lj = __shfl(lg2, gb + j);
        k += (lp > -2.0f) ? 1 : 0;
        lp += lj;
      }
    }
  }
  int n = k - 1;

  float mv[8] = {ma.x, ma.y, ma.z, ma.w, mb.x, mb.y, mb.z, mb.w};
  float s[8];
  int nv = 0;
  const uint32_t idx0 = (uint32_t)row * 128u + (uint32_t)(li * 8);
#pragma unroll
  for (int j = 0; j < 8; ++j) {
    uint32_t b0, b1;
    tf2x32(ku0, ku1, 0u, idx0 + (uint32_t)j, b0, b1);
    const bool valid = mv[j] > 0.5f;
    s[j] = valid ? u01(b0 ^ b1) : -1.0f;
    nv += valid ? 1 : 0;
  }
#pragma unroll
  for (int off = 8; off; off >>= 1) nv += __shfl_xor(nv, off);
  n = (nv > 1) ? min(n, nv - 1) : 0;

  uint32_t dropbits = 0u;
  for (int t = 0; t < n; ++t) {
    float bs = s[0];
    int bj = 0;
#pragma unroll
    for (int j = 1; j < 8; ++j) {
      if (s[j] > bs) { bs = s[j]; bj = j; }
    }
    int bc = (li << 3) + bj;
#pragma unroll
    for (int off = 8; off; off >>= 1) {
      const float os = __shfl_xor(bs, off);
      const int   oc = __shfl_xor(bc, off);
      if (os > bs || (os == bs && oc < bc)) { bs = os; bc = oc; }
    }
    const bool own = (bc >> 3) == li;
    const int  lj  = bc & 7;
#pragma unroll
    for (int j = 0; j < 8; ++j) {
      if (own && lj == j) { s[j] = -2.0f; dropbits |= (1u << j); }
    }
  }

  float xv[8] = {xa.x, xa.y, xa.z, xa.w, xb.x, xb.y, xb.z, xb.w};
#pragma unroll
  for (int j = 0; j < 8; ++j) {
    if ((dropbits >> j) & 1u) { xv[j] = 0.0f; mv[j] = 0.0f; }
  }
  float4 o;
  o.x = xv[0]; o.y = xv[1]; o.z = xv[2]; o.w = xv[3];
  *(float4*)(out + base) = o;
  o.x = xv[4]; o.y = xv[5]; o.z = xv[6]; o.w = xv[7];
  *(float4*)(out + base + 4) = o;
  o.x = mv[0]; o.y = mv[1]; o.z = mv[2]; o.w = mv[3];
  *(float4*)(out + NF + base) = o;
  o.x = mv[4]; o.y = mv[5]; o.z = mv[6]; o.w = mv[7];
  *(float4*)(out + NF + base + 4) = o;
}

extern "C" void kernel_launch(void* const* d_in, const int* in_sizes, int n_in,
                              void* d_out, int out_size, void* d_ws, size_t ws_size,
                              hipStream_t stream) {
  const float* x    = (const float*)d_in[0];
  const float* mask = (const float*)d_in[1];
  float* out = (float*)d_out;

  const int B = in_sizes[0] / 128;  // 500000

  // kp, ku = jax.random.split(jax.random.key(42)); key data = (0,42)
  // partitionable/foldlike: key[i] = full threefry output at counter (0, i)
  uint32_t kp0, kp1, ku0, ku1;
  tf2x32(0u, 42u, 0u, 0u, kp0, kp1);
  tf2x32(0u, 42u, 0u, 1u, ku0, ku1);

  // Host-precompute the Poisson rng-split chain (row-independent):
  // per iter: subkey = tf(rng; 0,1); rng = tf(rng; 0,0)
  PoisKeys pk;
  {
    uint32_t r0 = kp0, r1 = kp1;
    for (int it = 0; it < 32; ++it) {
      uint32_t s0, s1, t0, t1;
      tf2x32(r0, r1, 0u, 1u, s0, s1);
      tf2x32(r0, r1, 0u, 0u, t0, t1);
      pk.s0[it] = s0; pk.s1[it] = s1;
      r0 = t0; r1 = t1;
    }
  }

  if (ws_size < (size_t)B) {
    // fallback: fused single kernel (round-3 structure, 237 us)
    rfm_fused<<<(B + 15) / 16, 256, 0, stream>>>(x, mask, out, B, ku0, ku1, pk);
    return;
  }

  uint8_t* nraw = (uint8_t*)d_ws;
  pois_n_kernel<<<(B + 255) / 256, 256, 0, stream>>>(nraw, B, pk);
  rfm_main<<<(B + 63) / 64, 1024, 0, stream>>>(x, mask, nraw, out, B, ku0, ku1);
}

// Round 9
// 220.869 us; speedup vs baseline: 1.8020x; 1.0408x over previous
//
#include <hip/hip_runtime.h>
#include <cstdint>
#include <math.h>

// ---------------------------------------------------------------------------
// Bit-exact replication of jax.random with threefry_partitionable=True:
//   split(key)      -> key[i] = threefry(key; hi=0, lo=i)  (foldlike)
//   random_bits 32b -> o0 ^ o1 of threefry(key; hi=0, lo=flat_idx)
//   kp, ku = split(key(42)); key data = (0,42)
//   n_raw = poisson_knuth(kp, 2.0)[row]           (data-INDEPENDENT)
//   n = where(nv>1, min(n_raw, nv-1), 0)
//   scores = where(valid, uniform(ku,(B,128)), -1); drop top-n (stable ties)
//
// Round-8 post-mortem: block-local class partition works (230 us) but
// 1024-thread workgroups retire at the speed of their slowest (hash) wave, so
// copy waves pin resources and the scheduler can't backfill; max 2 blocks/CU.
// Round 9: SAME 64-row window + LDS partition, but FOUR 256-thread blocks per
// window (quarter q takes permuted slots q*16..q*16+15; wave 0 of each block
// redundantly recomputes the partition from nraw — 64-byte read + ballots).
// Hash rows pack to the front (npos ~ 38/64): quarters 0-1 pure hash, 3 pure
// copy -> copy blocks retire fast, scheduler backfills, finer CU-level
// overlap of memory-streaming and VALU-heavy blocks; 4-wave barriers.
// ---------------------------------------------------------------------------

#define DH __host__ __device__ __forceinline__

DH uint32_t rotl32(uint32_t v, uint32_t r) { return (v << r) | (v >> (32u - r)); }

// Threefry-2x32, 20 rounds (matches jax threefry2x32)
DH void tf2x32(uint32_t k0, uint32_t k1, uint32_t x0, uint32_t x1,
               uint32_t& o0, uint32_t& o1) {
  const uint32_t k2 = k0 ^ k1 ^ 0x1BD11BDAu;
  x0 += k0; x1 += k1;
  x0 += x1; x1 = rotl32(x1, 13); x1 ^= x0;
  x0 += x1; x1 = rotl32(x1, 15); x1 ^= x0;
  x0 += x1; x1 = rotl32(x1, 26); x1 ^= x0;
  x0 += x1; x1 = rotl32(x1,  6); x1 ^= x0;
  x0 += k1; x1 += k2 + 1u;
  x0 += x1; x1 = rotl32(x1, 17); x1 ^= x0;
  x0 += x1; x1 = rotl32(x1, 29); x1 ^= x0;
  x0 += x1; x1 = rotl32(x1, 16); x1 ^= x0;
  x0 += x1; x1 = rotl32(x1, 24); x1 ^= x0;
  x0 += k2; x1 += k0 + 2u;
  x0 += x1; x1 = rotl32(x1, 13); x1 ^= x0;
  x0 += x1; x1 = rotl32(x1, 15); x1 ^= x0;
  x0 += x1; x1 = rotl32(x1, 26); x1 ^= x0;
  x0 += x1; x1 = rotl32(x1,  6); x1 ^= x0;
  x0 += k0; x1 += k1 + 3u;
  x0 += x1; x1 = rotl32(x1, 17); x1 ^= x0;
  x0 += x1; x1 = rotl32(x1, 29); x1 ^= x0;
  x0 += x1; x1 = rotl32(x1, 16); x1 ^= x0;
  x0 += x1; x1 = rotl32(x1, 24); x1 ^= x0;
  x0 += k1; x1 += k2 + 4u;
  x0 += x1; x1 = rotl32(x1, 13); x1 ^= x0;
  x0 += x1; x1 = rotl32(x1, 15); x1 ^= x0;
  x0 += x1; x1 = rotl32(x1, 26); x1 ^= x0;
  x0 += x1; x1 = rotl32(x1,  6); x1 ^= x0;
  x0 += k2; x1 += k0 + 5u;
  o0 = x0; o1 = x1;
}

__device__ __forceinline__ float u01(uint32_t bits) {
  // jax.random.uniform: bitcast((bits>>9)|0x3f800000) - 1.0  (exact)
  return __uint_as_float((bits >> 9) | 0x3f800000u) - 1.0f;
}

struct PoisKeys { uint32_t s0[32]; uint32_t s1[32]; };

// ---- k1: Poisson n_raw -> u8[B], one lane per row, ROW ORDER.
// P(Poisson(2) >= 32) ~ 1e-25 -> 32 precomputed subkeys always suffice.
// (Bit-exact verified rounds 4/6/7/8.)
__global__ __launch_bounds__(256) void pois_n_kernel(
    uint8_t* __restrict__ nout, int B, PoisKeys pk) {
  const int row = (int)(blockIdx.x * 256u + threadIdx.x);
  if (row >= B) return;
  float lp = 0.0f;
  int k = 0;
  for (int it = 0; it < 32; ++it) {
    if (lp <= -2.0f) break;
    uint32_t b0, b1;
    tf2x32(pk.s0[it], pk.s1[it], 0u, (uint32_t)row, b0, b1);
    ++k;
    // correctly-rounded f32 log via f64; f32 accumulation like the reference
    lp += (float)log((double)u01(b0 ^ b1));
  }
  nout[row] = (uint8_t)(k - 1);
}

// ---- k2: main. 256-thread block = 4 waves = 16 groups x 16 lanes. Four
// blocks share a 64-consecutive-row window; block quarter q processes
// permuted slots q*16..q*16+15 (hash rows first -> class-pure blocks).
// Lane li owns cols li*8 .. li*8+7 (2x float4 per tensor).
__global__ __launch_bounds__(256) void rfm_main(
    const float* __restrict__ x, const float* __restrict__ mask,
    const uint8_t* __restrict__ nraw, float* __restrict__ out,
    int B, uint32_t ku0, uint32_t ku1) {
  __shared__ uint8_t s_n[64];
  __shared__ uint8_t s_perm[64];
  const int tid = (int)threadIdx.x;
  const int bid = (int)blockIdx.x;
  const int rowBase = (bid >> 2) * 64;
  const int q = bid & 3;
  const int nvalid = min(64, B - rowBase);

  if (tid < 64) {                    // exactly wave 0 (redundant per block)
    const bool vr = tid < nvalid;
    const int n = vr ? (int)nraw[rowBase + tid] : 0;
    s_n[tid] = (uint8_t)n;
    const bool cls = vr && (n > 0);
    const unsigned long long mh  = __ballot(cls);
    const unsigned long long mvr = __ballot(vr);
    // strictly-below lane mask (round-5 fix: lane 63 -> bits 0..62)
    const unsigned long long below = tid ? (~0ull >> (64 - tid)) : 0ull;
    const int npos = __popcll(mh);
    if (vr) {
      const int slot = cls ? __popcll(mh & below)
                           : npos + __popcll(mvr & (~mh) & below);
      s_perm[slot] = (uint8_t)tid;
    }
  }
  __syncthreads();

  const int g = q * 16 + (tid >> 4);  // this block's slot in the window
  if (g >= nvalid) return;
  const int li = tid & 15;
  const int j = (int)s_perm[g];
  const int row = rowBase + j;
  int n = (int)s_n[j];                // group-uniform; class-pure per wave

  const size_t base = (size_t)row * 128u + (size_t)(li * 8);
  const size_t NF = (size_t)B * 128u;

  const float4 ma = *(const float4*)(mask + base);
  const float4 mb = *(const float4*)(mask + base + 4);
  const float4 xa = *(const float4*)(x + base);
  const float4 xb = *(const float4*)(x + base + 4);
  float mv[8] = {ma.x, ma.y, ma.z, ma.w, mb.x, mb.y, mb.z, mb.w};
  float xv[8] = {xa.x, xa.y, xa.z, xa.w, xb.x, xb.y, xb.z, xb.w};

  if (n > 0) {
    // integer ranking key: valid -> (bits>>9)+1 in [1, 2^23], invalid -> 0.
    // Strictly monotone in the reference's float score; identical ties.
    uint32_t s[8];
    int nv = 0;
    const uint32_t idx0 = (uint32_t)row * 128u + (uint32_t)(li * 8);
#pragma unroll
    for (int jj = 0; jj < 8; ++jj) {
      uint32_t b0, b1;
      tf2x32(ku0, ku1, 0u, idx0 + (uint32_t)jj, b0, b1);
      const bool valid = mv[jj] > 0.5f;
      s[jj] = valid ? (((b0 ^ b1) >> 9) + 1u) : 0u;
      nv += valid ? 1 : 0;
    }
#pragma unroll
    for (int off = 8; off; off >>= 1) nv += __shfl_xor(nv, off);  // group sum

    n = (nv > 1) ? min(n, nv - 1) : 0;

    // drop the n highest-key positions (ties -> lower column index, matching
    // stable argsort; top-n always valid since n <= nv-1)
    uint32_t dropbits = 0u;
    for (int t = 0; t < n; ++t) {
      uint32_t bs = s[0];
      int bj = 0;
#pragma unroll
      for (int jj = 1; jj < 8; ++jj) {
        if (s[jj] > bs) { bs = s[jj]; bj = jj; }  // strict >: lowest j ties
      }
      int bc = (li << 3) + bj;
#pragma unroll
      for (int off = 8; off; off >>= 1) {         // group butterfly argmax
        const uint32_t os = __shfl_xor(bs, off);
        const int      oc = __shfl_xor(bc, off);
        if (os > bs || (os == bs && oc < bc)) { bs = os; bc = oc; }
      }
      const bool own = (bc >> 3) == li;
      const int  lj  = bc & 7;
#pragma unroll
      for (int jj = 0; jj < 8; ++jj) {            // static indices only
        if (own && lj == jj) { s[jj] = 0u; dropbits |= (1u << jj); }
      }
    }
#pragma unroll
    for (int jj = 0; jj < 8; ++jj) {
      if ((dropbits >> jj) & 1u) { xv[jj] = 0.0f; mv[jj] = 0.0f; }
    }
  }

  float4 o;
  o.x = xv[0]; o.y = xv[1]; o.z = xv[2]; o.w = xv[3];
  *(float4*)(out + base) = o;
  o.x = xv[4]; o.y = xv[5]; o.z = xv[6]; o.w = xv[7];
  *(float4*)(out + base + 4) = o;
  o.x = mv[0]; o.y = mv[1]; o.z = mv[2]; o.w = mv[3];
  *(float4*)(out + NF + base) = o;
  o.x = mv[4]; o.y = mv[5]; o.z = mv[6]; o.w = mv[7];
  *(float4*)(out + NF + base + 4) = o;
}

// ---- fallback (ws too small): round-3 fused kernel, no scratch needed.
__global__ __launch_bounds__(256) void rfm_fused(
    const float* __restrict__ x, const float* __restrict__ mask,
    float* __restrict__ out, int B,
    uint32_t ku0, uint32_t ku1, PoisKeys pk) {
  const int tid = (int)threadIdx.x;
  const int row = (int)blockIdx.x * 16 + (tid >> 4);
  if (row >= B) return;
  const int li = tid & 15;
  const int gb = (tid & 63) & 48;
  const size_t base = (size_t)row * 128u + (size_t)(li * 8);
  const size_t NF = (size_t)B * 128u;

  const float4 ma = *(const float4*)(mask + base);
  const float4 mb = *(const float4*)(mask + base + 4);
  const float4 xa = *(const float4*)(x + base);
  const float4 xb = *(const float4*)(x + base + 4);

  float lg;
  {
    uint32_t b0, b1;
    tf2x32(pk.s0[li], pk.s1[li], 0u, (uint32_t)row, b0, b1);
    lg = (float)log((double)u01(b0 ^ b1));
  }
  float lp = 0.0f;
  int k = 0;
#pragma unroll
  for (int j = 0; j < 8; ++j) {
    const float lj = __shfl(lg, gb + j);
    k += (lp > -2.0f) ? 1 : 0;
    lp += lj;
  }
  if (lp > -2.0f) {
#pragma unroll
    for (int j = 8; j < 16; ++j) {
      const float lj = __shfl(lg, gb + j);
      k += (lp > -2.0f) ? 1 : 0;
      lp += lj;
    }
    if (lp > -2.0f) {
      uint32_t c0, c1;
      const int i2 = 16 + (li & 7);
      tf2x32(pk.s0[i2], pk.s1[i2], 0u, (uint32_t)row, c0, c1);
      const float lg2 = (float)log((double)u01(c0 ^ c1));
#pragma unroll
      for (int j = 0; j < 8; ++j) {
        const float lj = __shfl(lg2, gb + j);
        k += (lp > -2.0f) ? 1 : 0;
        lp += lj;
      }
    }
  }
  int n = k - 1;

  float mv[8] = {ma.x, ma.y, ma.z, ma.w, mb.x, mb.y, mb.z, mb.w};
  float s[8];
  int nv = 0;
  const uint32_t idx0 = (uint32_t)row * 128u + (uint32_t)(li * 8);
#pragma unroll
  for (int j = 0; j < 8; ++j) {
    uint32_t b0, b1;
    tf2x32(ku0, ku1, 0u, idx0 + (uint32_t)j, b0, b1);
    const bool valid = mv[j] > 0.5f;
    s[j] = valid ? u01(b0 ^ b1) : -1.0f;
    nv += valid ? 1 : 0;
  }
#pragma unroll
  for (int off = 8; off; off >>= 1) nv += __shfl_xor(nv, off);
  n = (nv > 1) ? min(n, nv - 1) : 0;

  uint32_t dropbits = 0u;
  for (int t = 0; t < n; ++t) {
    float bs = s[0];
    int bj = 0;
#pragma unroll
    for (int j = 1; j < 8; ++j) {
      if (s[j] > bs) { bs = s[j]; bj = j; }
    }
    int bc = (li << 3) + bj;
#pragma unroll
    for (int off = 8; off; off >>= 1) {
      const float os = __shfl_xor(bs, off);
      const int   oc = __shfl_xor(bc, off);
      if (os > bs || (os == bs && oc < bc)) { bs = os; bc = oc; }
    }
    const bool own = (bc >> 3) == li;
    const int  lj  = bc & 7;
#pragma unroll
    for (int j = 0; j < 8; ++j) {
      if (own && lj == j) { s[j] = -2.0f; dropbits |= (1u << j); }
    }
  }

  float xv[8] = {xa.x, xa.y, xa.z, xa.w, xb.x, xb.y, xb.z, xb.w};
#pragma unroll
  for (int j = 0; j < 8; ++j) {
    if ((dropbits >> j) & 1u) { xv[j] = 0.0f; mv[j] = 0.0f; }
  }
  float4 o;
  o.x = xv[0]; o.y = xv[1]; o.z = xv[2]; o.w = xv[3];
  *(float4*)(out + base) = o;
  o.x = xv[4]; o.y = xv[5]; o.z = xv[6]; o.w = xv[7];
  *(float4*)(out + base + 4) = o;
  o.x = mv[0]; o.y = mv[1]; o.z = mv[2]; o.w = mv[3];
  *(float4*)(out + NF + base) = o;
  o.x = mv[4]; o.y = mv[5]; o.z = mv[6]; o.w = mv[7];
  *(float4*)(out + NF + base + 4) = o;
}

extern "C" void kernel_launch(void* const* d_in, const int* in_sizes, int n_in,
                              void* d_out, int out_size, void* d_ws, size_t ws_size,
                              hipStream_t stream) {
  const float* x    = (const float*)d_in[0];
  const float* mask = (const float*)d_in[1];
  float* out = (float*)d_out;

  const int B = in_sizes[0] / 128;  // 500000

  // kp, ku = jax.random.split(jax.random.key(42)); key data = (0,42)
  // partitionable/foldlike: key[i] = full threefry output at counter (0, i)
  uint32_t kp0, kp1, ku0, ku1;
  tf2x32(0u, 42u, 0u, 0u, kp0, kp1);
  tf2x32(0u, 42u, 0u, 1u, ku0, ku1);

  // Host-precompute the Poisson rng-split chain (row-independent):
  // per iter: subkey = tf(rng; 0,1); rng = tf(rng; 0,0)
  PoisKeys pk;
  {
    uint32_t r0 = kp0, r1 = kp1;
    for (int it = 0; it < 32; ++it) {
      uint32_t s0, s1, t0, t1;
      tf2x32(r0, r1, 0u, 1u, s0, s1);
      tf2x32(r0, r1, 0u, 0u, t0, t1);
      pk.s0[it] = s0; pk.s1[it] = s1;
      r0 = t0; r1 = t1;
    }
  }

  if (ws_size < (size_t)B) {
    // fallback: fused single kernel (round-3 structure, 237 us)
    rfm_fused<<<(B + 15) / 16, 256, 0, stream>>>(x, mask, out, B, ku0, ku1, pk);
    return;
  }

  uint8_t* nraw = (uint8_t*)d_ws;
  pois_n_kernel<<<(B + 255) / 256, 256, 0, stream>>>(nraw, B, pk);

  const int windows = (B + 63) / 64;
  rfm_main<<<windows * 4, 256, 0, stream>>>(x, mask, nraw, out, B, ku0, ku1);
}